// Round 4
// baseline (477.794 us; speedup 1.0000x reference)
//
#include <hip/hip_runtime.h>

// GaussianBlur2D: separable 201-tap Gaussian (sigma=25, zero-pad), fp32.
// T=64, H=544, W=960.
//   vpass: vertical, 32 rows/thread, fixed-trip masked loop (unroll 8).
//   hpass: horizontal in-place, LDS float4 sliding window, 8 out/thread,
//          j-loop FULLY unrolled -> all 1664 taps are inline literals
//          (no s_load chains, ds_reads free to schedule ahead).
// fp32-VALU practical floor ~300us total (13.4e9 padded FMA at ~103 TF).

#define HH   544
#define WWD  960
#define PADC 100
#define RV   32

// ---- compile-time Gaussian (double Taylor exp, rounded to f32) ----
constexpr double cexp_taylor(double x) {
  double term = 1.0, sum = 1.0;
  for (int n = 1; n < 120; ++n) { term *= x / n; sum += term; }
  return sum;
}
constexpr float gaussk(int k) {            // tap k in [0,200], else 0
  if (k < 0 || k > 200) return 0.0f;
  double r = (double)(k - PADC);
  return (float)(cexp_taylor(-(r * r) / (2.0 * 25.0 * 25.0))
                 / (25.0 * 2.5066282746310002));
}
// vpass table: tap for (bb, r) = gaussk(bb - r) = KTZ.v[bb + 31 - r],
// bb in [0,232), r in [0,32) -> idx in [0,262]. Zero-padded.
struct KTabZ { float v[272]; };
constexpr KTabZ make_ktz() {
  KTabZ t{};
  for (int i = 0; i < 272; ++i) t.v[i] = gaussk(i - 31);
  return t;
}
__device__ __constant__ KTabZ KTZ = make_ktz();

// hpass taps resolved at compile time after full unroll (inline literals).
struct KTabE { float v[216]; };
constexpr KTabE KTE = [] {
  KTabE t{};
  for (int i = 0; i < 216; ++i) t.v[i] = gaussk(i - 8);
  return t;
}();

// ---------------- pass 1: vertical conv along H ----------------
// 1D grid of 2176 blocks decoded so frame t lands on XCD t%8 (2.09MB frame
// fits one XCD's 4MiB L2; all 34 blocks of a frame share halos there).
// Thread owns 2 columns x 32 rows. Fixed 232-trip input-major loop:
// clamped row address + uniform zero mask, unroll 8 -> tap s_loads
// amortize over 512 FMAs per body.
__global__ __launch_bounds__(256, 4) void vpass(const float* __restrict__ x,
                                                float* __restrict__ y) {
  const int lid = blockIdx.x;          // 0..2175
  const int xcd = lid & 7;
  const int s   = lid >> 3;            // 0..271
  const int f   = s / 34;              // 0..7
  const int r34 = s - 34 * f;          // 0..33
  const int t   = (f << 3) | xcd;      // frame
  const int wt  = r34 & 1;
  const int hc  = r34 >> 1;            // 0..16
  const int tid = threadIdx.x;
  const int w   = 2 * (wt * 256 + tid);
  const int h0  = hc * RV;
  if (w >= WWD) return;

  const float* xw = x + (size_t)t * (HH * WWD) + w;

  float ax[RV], ay[RV];
#pragma unroll
  for (int r = 0; r < RV; ++r) { ax[r] = 0.f; ay[r] = 0.f; }

#pragma unroll 8
  for (int bb = 0; bb < 232; ++bb) {           // b = bb - 100
    const int h  = h0 + bb - PADC;
    const int hcl = (h < 0) ? 0 : ((h > HH - 1) ? HH - 1 : h);
    const float m = (h == hcl) ? 1.0f : 0.0f;  // uniform row-valid mask
    float2 v = *(const float2*)(xw + (size_t)hcl * WWD);
    v.x *= m; v.y *= m;
    const float* kb = &KTZ.v[bb + 31];
#pragma unroll
    for (int r = 0; r < RV; ++r) {
      const float kk = kb[-r];                 // wave-uniform scalar
      ax[r] = fmaf(kk, v.x, ax[r]);
      ay[r] = fmaf(kk, v.y, ay[r]);
    }
  }

  float* yp = y + (size_t)t * (HH * WWD) + (size_t)h0 * WWD + w;
#pragma unroll
  for (int r = 0; r < RV; ++r) {
    float2 o; o.x = ax[r]; o.y = ay[r];
    *(float2*)(yp + (size_t)r * WWD) = o;
  }
}

// ---------------- pass 2: horizontal conv along W, in-place ----------------
// Block = 256 threads = 2 rows; lt in [0,120) owns 8 consecutive w of one row.
// Row staged in LDS as 290 float4 blocks (25 zero | 240 data | 25 zero), XOR
// swizzled (q ^ (q>>3)&1) so stride-2-block sliding reads spread across all
// 8 bank-quads (2-way max = free). j-loop fully unrolled: 52 ds_read_b128 +
// 1664 literal-tap FMA per thread, no scalar-mem dependencies in the body.
__device__ __forceinline__ int swz(int q) { return q ^ ((q >> 3) & 1); }

__global__ __launch_bounds__(256, 4) void hpass(float* __restrict__ y) {
  __shared__ __align__(16) float4 row[2][292];
  const int tid = threadIdx.x;
  const int hh  = tid >> 7;
  const int lt  = tid & 127;
  float* yp = y + (size_t)(blockIdx.x * 2 + hh) * WWD;

  const float4 z4 = {0.f, 0.f, 0.f, 0.f};
  if (lt < 25) {
    row[hh][swz(lt)] = z4;                      // left pad blocks [0,25)
  } else if (lt >= 32 && lt < 57) {
    row[hh][swz(265 + lt - 32)] = z4;           // right pad blocks [265,290)
  }
  if (lt < 120) {
    const int q0 = 25 + 2 * lt;                 // data blocks [25,265)
    row[hh][swz(q0)]     = *(const float4*)(yp + 8 * lt);
    row[hh][swz(q0 + 1)] = *(const float4*)(yp + 8 * lt + 4);
  }
  __syncthreads();

  if (lt < 120) {
    float a0=0.f,a1=0.f,a2=0.f,a3=0.f,a4=0.f,a5=0.f,a6=0.f,a7=0.f;
#pragma unroll
    for (int j = 0; j < 52; ++j) {              // FULL unroll: taps = literals
      const float4 v = row[hh][swz(2 * lt + j)];
      {
        const float xv = v.x;
        a0 = fmaf(KTE.v[4*j+8],  xv, a0);  a1 = fmaf(KTE.v[4*j+7],  xv, a1);
        a2 = fmaf(KTE.v[4*j+6],  xv, a2);  a3 = fmaf(KTE.v[4*j+5],  xv, a3);
        a4 = fmaf(KTE.v[4*j+4],  xv, a4);  a5 = fmaf(KTE.v[4*j+3],  xv, a5);
        a6 = fmaf(KTE.v[4*j+2],  xv, a6);  a7 = fmaf(KTE.v[4*j+1],  xv, a7);
      }
      {
        const float xv = v.y;
        a0 = fmaf(KTE.v[4*j+9],  xv, a0);  a1 = fmaf(KTE.v[4*j+8],  xv, a1);
        a2 = fmaf(KTE.v[4*j+7],  xv, a2);  a3 = fmaf(KTE.v[4*j+6],  xv, a3);
        a4 = fmaf(KTE.v[4*j+5],  xv, a4);  a5 = fmaf(KTE.v[4*j+4],  xv, a5);
        a6 = fmaf(KTE.v[4*j+3],  xv, a6);  a7 = fmaf(KTE.v[4*j+2],  xv, a7);
      }
      {
        const float xv = v.z;
        a0 = fmaf(KTE.v[4*j+10], xv, a0);  a1 = fmaf(KTE.v[4*j+9],  xv, a1);
        a2 = fmaf(KTE.v[4*j+8],  xv, a2);  a3 = fmaf(KTE.v[4*j+7],  xv, a3);
        a4 = fmaf(KTE.v[4*j+6],  xv, a4);  a5 = fmaf(KTE.v[4*j+5],  xv, a5);
        a6 = fmaf(KTE.v[4*j+4],  xv, a6);  a7 = fmaf(KTE.v[4*j+3],  xv, a7);
      }
      {
        const float xv = v.w;
        a0 = fmaf(KTE.v[4*j+11], xv, a0);  a1 = fmaf(KTE.v[4*j+10], xv, a1);
        a2 = fmaf(KTE.v[4*j+9],  xv, a2);  a3 = fmaf(KTE.v[4*j+8],  xv, a3);
        a4 = fmaf(KTE.v[4*j+7],  xv, a4);  a5 = fmaf(KTE.v[4*j+6],  xv, a5);
        a6 = fmaf(KTE.v[4*j+5],  xv, a6);  a7 = fmaf(KTE.v[4*j+4],  xv, a7);
      }
    }
    float4 o0; o0.x = a0; o0.y = a1; o0.z = a2; o0.w = a3;
    float4 o1; o1.x = a4; o1.y = a5; o1.z = a6; o1.w = a7;
    *(float4*)(yp + 8 * lt)     = o0;
    *(float4*)(yp + 8 * lt + 4) = o1;
  }
}

extern "C" void kernel_launch(void* const* d_in, const int* in_sizes, int n_in,
                              void* d_out, int out_size, void* d_ws, size_t ws_size,
                              hipStream_t stream) {
  const float* x = (const float*)d_in[0];
  float* out = (float*)d_out;
  (void)d_ws; (void)ws_size; (void)in_sizes; (void)n_in; (void)out_size;

  vpass<<<dim3(2 * (HH / RV) * 64), dim3(256), 0, stream>>>(x, out);
  hpass<<<dim3(64 * HH / 2), dim3(256), 0, stream>>>(out);
}